// Round 17
// baseline (214.464 us; speedup 1.0000x reference)
//
#include <hip/hip_runtime.h>

#define TPB 256
#define NB 391            // ceil(100000/256) coarse buckets of 256 nodes
#define CH 2048           // edges per k_placeA block (782 blocks, ~29 KB LDS)
#define BS 4736           // fixed bucket stride (mean 4096 + 10 sigma)

// ---- bf16 helpers (manual RNE pack, shift unpack) ----

__device__ __forceinline__ unsigned bpack(float a, float b) {
    unsigned ua = __float_as_uint(a), ub = __float_as_uint(b);
    ua = (ua + 0x7fffu + ((ua >> 16) & 1u)) >> 16;
    ub = (ub + 0x7fffu + ((ub >> 16) & 1u)) >> 16;
    return ua | (ub << 16);
}
__device__ __forceinline__ float blo(unsigned u) { return __uint_as_float(u << 16); }
__device__ __forceinline__ float bhi(unsigned u) { return __uint_as_float(u & 0xffff0000u); }

// ---------------- chunked coarse bucket sort, LDS-staged grouped writes ----
// packs each edge as  src | ((dst & 255) << 20); dst stashed in LDS so each
// global input word is read exactly once. gcur is ZERO-BASED (memset),
// global slot = b*BS + within-bucket offset. CH=2048 keeps LDS ~29 KB ->
// 5 blocks/CU (20 waves/CU) for this latency-bound kernel.

__global__ __launch_bounds__(TPB) void k_placeA(const int* __restrict__ src,
                                                const int* __restrict__ dst,
                                                unsigned* __restrict__ gcur,
                                                unsigned* __restrict__ bkt, int E) {
    __shared__ unsigned val[CH];
    __shared__ unsigned dstS[CH];
    __shared__ unsigned short bid[CH];
    __shared__ unsigned cnt[512], loff[512], lcur[512], basev[512];
    __shared__ unsigned tsum[TPB];
    int t = threadIdx.x;
    int c0 = blockIdx.x * CH;
    int n = E - c0; if (n > CH) n = CH;

    for (int b = t; b < 512; b += TPB) { cnt[b] = 0; lcur[b] = 0; }
    __syncthreads();
    for (int i = t; i < n; i += TPB) {
        unsigned d = (unsigned)dst[c0 + i];
        dstS[i] = d;
        atomicAdd(&cnt[d >> 8], 1u);
    }
    __syncthreads();
    for (int b = t; b < NB; b += TPB)
        basev[b] = cnt[b] ? atomicAdd(&gcur[b], cnt[b]) : 0u;
    unsigned a0 = cnt[2 * t], a1 = cnt[2 * t + 1];
    tsum[t] = a0 + a1;
    __syncthreads();
#pragma unroll
    for (int o = 1; o < TPB; o <<= 1) {
        unsigned v = (t >= o) ? tsum[t - o] : 0u;
        __syncthreads();
        tsum[t] += v;
        __syncthreads();
    }
    unsigned ex = tsum[t] - (a0 + a1);
    loff[2 * t] = ex; loff[2 * t + 1] = ex + a0;
    __syncthreads();
    for (int i = t; i < n; i += TPB) {
        unsigned s = (unsigned)src[c0 + i];
        unsigned d = dstS[i];
        unsigned b = d >> 8;
        unsigned r = atomicAdd(&lcur[b], 1u);
        unsigned slot = loff[b] + r;
        val[slot] = s | ((d & 255u) << 20);
        bid[slot] = (unsigned short)b;
    }
    __syncthreads();
    for (int i = t; i < n; i += TPB) {
        unsigned b = bid[i];
        bkt[(size_t)b * BS + basev[b] + ((unsigned)i - loff[b])] = val[i];
    }
}

// ---------------- fine sort within bucket -> rp2 + dinv + xs4 --------------
// 512 threads; key = (dst&255, src>>13): per-node neighbor lists come out
// SORTED BY 8K-NODE SRC CHUNK (1 MB of gb each) -> machine-wide temporal
// locality in the downstream pulls. 4096 bins.

__global__ __launch_bounds__(512) void k_fineS(const unsigned* __restrict__ bkt,
                                               const unsigned* __restrict__ gcur,
                                               const float* __restrict__ x,
                                               int2* __restrict__ rp2,
                                               int* __restrict__ ssrc,
                                               float* __restrict__ dinv,
                                               float4* __restrict__ xs4, int N) {
    __shared__ unsigned bins[4096];
    __shared__ unsigned tsum[512];
    __shared__ unsigned degS[256];
    __shared__ unsigned bs[BS];
    int t = threadIdx.x, b = blockIdx.x;
    for (int i = t; i < 4096; i += 512) bins[i] = 0;
    __syncthreads();
    int p0 = b * BS;
    int n = (int)gcur[b];                     // zero-based count
    for (int i = t; i < n; i += 512) {
        unsigned u = bkt[p0 + i];
        bs[i] = u;
        unsigned bin = ((u >> 20) << 4) | ((u & 0xFFFFFu) >> 13);
        atomicAdd(&bins[bin], 1u);
    }
    __syncthreads();
    // read counts (8 bins/thread) before in-place scan overwrite
    unsigned s[8], pre[8];
#pragma unroll
    for (int i = 0; i < 8; ++i) s[i] = bins[8 * t + i];
    if (t < 256) {
        unsigned d = 0;
#pragma unroll
        for (int i = 0; i < 16; ++i) d += bins[(t << 4) + i];
        degS[t] = d;
    }
    unsigned tot = 0;
#pragma unroll
    for (int i = 0; i < 8; ++i) { pre[i] = tot; tot += s[i]; }
    tsum[t] = tot;
    __syncthreads();
#pragma unroll
    for (int o = 1; o < 512; o <<= 1) {
        unsigned v = (t >= o) ? tsum[t - o] : 0u;
        __syncthreads();
        tsum[t] += v;
        __syncthreads();
    }
    unsigned ex = tsum[t] - tot;
#pragma unroll
    for (int i = 0; i < 8; ++i) bins[8 * t + i] = ex + pre[i];
    __syncthreads();
    if (t < 256) {
        int node = (b << 8) + t;
        if (node < N) {
            unsigned c = degS[t];
            int beg = p0 + (int)bins[t << 4];       // exclusive prefix at node's first bin
            rp2[node] = make_int2(beg, beg + (int)c);
            float dv = rsqrtf((float)(c + 1u));     // +1 = self-loop
            dinv[node] = dv;
            float4 xv;
            xv.x = x[node * 3 + 0] * dv;
            xv.y = x[node * 3 + 1] * dv;
            xv.z = x[node * 3 + 2] * dv;
            xv.w = 0.f;
            xs4[node] = xv;
        }
    }
    __syncthreads();                                // node-beg reads before cursor bumps
    for (int i = t; i < n; i += 512) {
        unsigned u = bs[i];
        unsigned bin = ((u >> 20) << 4) | ((u & 0xFFFFFu) >> 13);
        unsigned r = atomicAdd(&bins[bin], 1u);     // bins now = running cursors
        ssrc[p0 + (int)r] = (int)(u & 0xFFFFFu);
    }
}

// ---------------- fused layer 1 + layer-2 linear (4 lanes/node) ------------
// lane c: aggregates component c of xs4; q broadcast in-group; h1 on the fly
// (scalar W1 path); 16 output features from LDS-staged W2 packed as BF16
// pairs (halves LDS traffic of the dense phase); stores bf16 node-major.

__global__ __launch_bounds__(TPB) void k_l1q(const float* __restrict__ xs4,
                                             const int2* __restrict__ rp2,
                                             const int* __restrict__ ssrc,
                                             const float* __restrict__ dinv,
                                             const float* __restrict__ W1,
                                             const float* __restrict__ b1,
                                             const float* __restrict__ W2,
                                             uint4* __restrict__ gb, int N) {
    __shared__ unsigned Ws2[2048];                  // W2 as bf16 pairs
    for (int i = threadIdx.x; i < 2048; i += TPB)
        Ws2[i] = bpack(W2[2 * i], W2[2 * i + 1]);
    __syncthreads();                                // before any early return!
    int tid = blockIdx.x * TPB + threadIdx.x;
    int node = tid >> 2, c = tid & 3;
    if (node >= N) return;
    int2 r = rp2[node];
    float acc = xs4[tid];                           // xs4[(node<<2)+c], self-loop
    int j = r.x;
    for (; j + 3 < r.y; j += 4) {
        int s0 = ssrc[j], s1 = ssrc[j+1], s2 = ssrc[j+2], s3 = ssrc[j+3];
        acc += (xs4[(s0 << 2) + c] + xs4[(s1 << 2) + c])
             + (xs4[(s2 << 2) + c] + xs4[(s3 << 2) + c]);
    }
    for (; j < r.y; ++j) acc += xs4[(ssrc[j] << 2) + c];
    float dv = dinv[node];
    acc *= dv;
    int base = (threadIdx.x & 63) & ~3;             // my 4-lane group
    float q0 = __shfl(acc, base + 0, 64);
    float q1 = __shfl(acc, base + 1, 64);
    float q2 = __shfl(acc, base + 2, 64);

    float o[16];
#pragma unroll
    for (int i = 0; i < 16; ++i) o[i] = 0.f;
    const int cofs8 = c << 3;                       // 8 u32 per 16 features
    for (int kb = 0; kb < 16; ++kb) {
        int k0 = __builtin_amdgcn_readfirstlane(kb) << 2;
        const float* W1k = W1 + k0;                 // W1[cc*64 + k0+kk]
        const float* b1k = b1 + k0;
        float h[4];
        h[0] = fmaxf(fmaf(q0, W1k[0], fmaf(q1, W1k[64], fmaf(q2, W1k[128], b1k[0]))), 0.f);
        h[1] = fmaxf(fmaf(q0, W1k[1], fmaf(q1, W1k[65], fmaf(q2, W1k[129], b1k[1]))), 0.f);
        h[2] = fmaxf(fmaf(q0, W1k[2], fmaf(q1, W1k[66], fmaf(q2, W1k[130], b1k[2]))), 0.f);
        h[3] = fmaxf(fmaf(q0, W1k[3], fmaf(q1, W1k[67], fmaf(q2, W1k[131], b1k[3]))), 0.f);
#pragma unroll
        for (int kk = 0; kk < 4; ++kk) {
            const uint4* Wp = (const uint4*)(Ws2 + ((k0 + kk) << 5) + cofs8);
            uint4 wA = Wp[0];                       // 4 distinct addrs/wave -> broadcast
            uint4 wB = Wp[1];
            float hv = h[kk];
            o[0]  = fmaf(hv, blo(wA.x), o[0]);  o[1]  = fmaf(hv, bhi(wA.x), o[1]);
            o[2]  = fmaf(hv, blo(wA.y), o[2]);  o[3]  = fmaf(hv, bhi(wA.y), o[3]);
            o[4]  = fmaf(hv, blo(wA.z), o[4]);  o[5]  = fmaf(hv, bhi(wA.z), o[5]);
            o[6]  = fmaf(hv, blo(wA.w), o[6]);  o[7]  = fmaf(hv, bhi(wA.w), o[7]);
            o[8]  = fmaf(hv, blo(wB.x), o[8]);  o[9]  = fmaf(hv, bhi(wB.x), o[9]);
            o[10] = fmaf(hv, blo(wB.y), o[10]); o[11] = fmaf(hv, bhi(wB.y), o[11]);
            o[12] = fmaf(hv, blo(wB.z), o[12]); o[13] = fmaf(hv, bhi(wB.z), o[13]);
            o[14] = fmaf(hv, blo(wB.w), o[14]); o[15] = fmaf(hv, bhi(wB.w), o[15]);
        }
    }
    uint4 v0, v1;
    v0.x = bpack(o[0] * dv,  o[1] * dv);
    v0.y = bpack(o[2] * dv,  o[3] * dv);
    v0.z = bpack(o[4] * dv,  o[5] * dv);
    v0.w = bpack(o[6] * dv,  o[7] * dv);
    v1.x = bpack(o[8] * dv,  o[9] * dv);
    v1.y = bpack(o[10] * dv, o[11] * dv);
    v1.z = bpack(o[12] * dv, o[13] * dv);
    v1.w = bpack(o[14] * dv, o[15] * dv);
    uint4* gp = gb + ((size_t)node << 3) + (c << 1);
    gp[0] = v0;
    gp[1] = v1;
}

// ---------------- fused layer-2 pull (bf16) + bias/relu + layer-3 linear ---
// 8 lanes/node, 16 B (8 bf16 features) per lane; full in-wave W3 reduction.
// Neighbor lists are src-chunk-sorted -> machine-wide temporal L2 locality.

__global__ __launch_bounds__(TPB) void k_p2fb(const uint4* __restrict__ gb,
                                              const int2* __restrict__ rp2,
                                              const int* __restrict__ ssrc,
                                              const float* __restrict__ dinv,
                                              const float* __restrict__ b2,
                                              const float* __restrict__ W3,
                                              float* __restrict__ q4, int N) {
    int tid = blockIdx.x * TPB + threadIdx.x;
    int node = tid >> 3, q = tid & 7;
    if (node >= N) return;
    int2 r = rp2[node];
    int beg = r.x, end = r.y;
    float a[8];
    {
        uint4 u = gb[((size_t)node << 3) + q];  // self-loop
        a[0] = blo(u.x); a[1] = bhi(u.x);
        a[2] = blo(u.y); a[3] = bhi(u.y);
        a[4] = blo(u.z); a[5] = bhi(u.z);
        a[6] = blo(u.w); a[7] = bhi(u.w);
    }
    int j = beg;
    for (; j + 3 < end; j += 4) {
        int s0 = ssrc[j], s1 = ssrc[j+1], s2 = ssrc[j+2], s3 = ssrc[j+3];
        uint4 u0 = gb[((size_t)s0 << 3) + q];
        uint4 u1 = gb[((size_t)s1 << 3) + q];
        uint4 u2 = gb[((size_t)s2 << 3) + q];
        uint4 u3 = gb[((size_t)s3 << 3) + q];
        a[0] += (blo(u0.x) + blo(u1.x)) + (blo(u2.x) + blo(u3.x));
        a[1] += (bhi(u0.x) + bhi(u1.x)) + (bhi(u2.x) + bhi(u3.x));
        a[2] += (blo(u0.y) + blo(u1.y)) + (blo(u2.y) + blo(u3.y));
        a[3] += (bhi(u0.y) + bhi(u1.y)) + (bhi(u2.y) + bhi(u3.y));
        a[4] += (blo(u0.z) + blo(u1.z)) + (blo(u2.z) + blo(u3.z));
        a[5] += (bhi(u0.z) + bhi(u1.z)) + (bhi(u2.z) + bhi(u3.z));
        a[6] += (blo(u0.w) + blo(u1.w)) + (blo(u2.w) + blo(u3.w));
        a[7] += (bhi(u0.w) + bhi(u1.w)) + (bhi(u2.w) + bhi(u3.w));
    }
    for (; j < end; ++j) {
        uint4 u = gb[((size_t)ssrc[j] << 3) + q];
        a[0] += blo(u.x); a[1] += bhi(u.x);
        a[2] += blo(u.y); a[3] += bhi(u.y);
        a[4] += blo(u.z); a[5] += bhi(u.z);
        a[6] += blo(u.w); a[7] += bhi(u.w);
    }
    float dv = dinv[node];
    int f0 = q << 3;
    const float* bb = b2 + f0;
    const float* Wr = W3 + f0 * 3;              // W3[(f0+i)*3 + c]
    float p0 = 0.f, p1 = 0.f, p2 = 0.f;
#pragma unroll
    for (int i = 0; i < 8; ++i) {
        float h = fmaxf(fmaf(a[i], dv, bb[i]), 0.f);
        p0 = fmaf(h, Wr[3*i+0], p0);
        p1 = fmaf(h, Wr[3*i+1], p1);
        p2 = fmaf(h, Wr[3*i+2], p2);
    }
#pragma unroll
    for (int off = 1; off < 8; off <<= 1) {     // reduce across the 8-lane group
        p0 += __shfl_xor(p0, off, 64);
        p1 += __shfl_xor(p1, off, 64);
        p2 += __shfl_xor(p2, off, 64);
    }
    if (q < 4) {
        float v = (q == 0) ? p0 * dv : (q == 1) ? p1 * dv : (q == 2) ? p2 * dv : 0.f;
        q4[((size_t)node << 2) + q] = v;
    }
}

// ---------------- layer-3 pull with output epilogue ----------------

__global__ __launch_bounds__(TPB) void k_pull3o(const float* __restrict__ g34,
                                                const int2* __restrict__ rp2,
                                                const int* __restrict__ ssrc,
                                                const float* __restrict__ dinv,
                                                const float* __restrict__ b3,
                                                float* __restrict__ out, int N) {
    int tid = blockIdx.x * TPB + threadIdx.x;
    int node = tid >> 2, c = tid & 3;
    if (node >= N) return;
    int2 r = rp2[node];
    int beg = r.x, end = r.y;
    float acc = g34[tid];                       // self-loop
    int j = beg;
    for (; j + 3 < end; j += 4) {
        int s0 = ssrc[j], s1 = ssrc[j+1], s2 = ssrc[j+2], s3 = ssrc[j+3];
        acc += (g34[(s0 << 2) + c] + g34[(s1 << 2) + c])
             + (g34[(s2 << 2) + c] + g34[(s3 << 2) + c]);
    }
    for (; j < end; ++j) acc += g34[(ssrc[j] << 2) + c];
    if (c < 3) out[(size_t)node * 3 + c] = dinv[node] * acc + b3[c];
}

extern "C" void kernel_launch(void* const* d_in, const int* in_sizes, int n_in,
                              void* d_out, int out_size, void* d_ws, size_t ws_size,
                              hipStream_t stream) {
    const float* x  = (const float*)d_in[0];
    const int*   ei = (const int*)  d_in[1];
    const float* W1 = (const float*)d_in[2];
    const float* b1 = (const float*)d_in[3];
    const float* W2 = (const float*)d_in[4];
    const float* b2 = (const float*)d_in[5];
    const float* W3 = (const float*)d_in[6];
    const float* b3 = (const float*)d_in[7];
    float* out = (float*)d_out;

    const int N = in_sizes[0] / 3;       // 100000
    const int E = in_sizes[1] / 2;       // 1600000
    const int* srcI = ei;
    const int* dstI = ei + E;

    // workspace layout (4-byte units), 16B-aligned segments
    float*    ws   = (float*)d_ws;
    unsigned* gcur = (unsigned*)ws;                         // @0        [512]
    int2*     rp2  = (int2*)    (ws + 512);                 // [N]  (2N u32)
    float*    dinv = ws + 512 + 2 * (size_t)N;              // [N]
    int*      ssrc = (int*)     (dinv + N);                 // [NB*BS]
    float*    xs4  = (float*)(ssrc + (size_t)NB * BS + 4);  // [4N]
    float*    q4   = xs4 + (size_t)N * 4;                   // [4N]
    unsigned* gb   = (unsigned*)(q4 + (size_t)N * 4);       // [32N] bf16 g
    unsigned* bkt  = gb + (size_t)N * 32;                   // [NB*BS]

    int gPlace = (E + CH - 1) / CH;                         // 782
    int gS3    = (N * 4 + TPB - 1) / TPB;                   // 1563
    int gP2    = (int)(((size_t)N * 8 + TPB - 1) / TPB);    // 3125

    // preprocessing: fixed-stride bucket sort -> rp2 + dinv + xs4
    hipMemsetAsync(gcur, 0, 512 * sizeof(unsigned), stream);
    k_placeA<<<gPlace, TPB, 0, stream>>>(srcI, dstI, gcur, bkt, E);
    k_fineS <<<NB,     512, 0, stream>>>(bkt, gcur, x, rp2, ssrc, dinv,
                                         (float4*)xs4, N);

    // layer 1 + layer-2 linear fused (4 lanes/node); g stored bf16 node-major
    k_l1q<<<gS3, TPB, 0, stream>>>(xs4, rp2, ssrc, dinv,
                                   W1, b1, W2, (uint4*)gb, N);

    // layer-2 pull (bf16) + bias/relu + layer-3 linear fused
    k_p2fb<<<gP2, TPB, 0, stream>>>((const uint4*)gb, rp2, ssrc, dinv,
                                    b2, W3, q4, N);

    // layer-3 pull (+bias fused)
    k_pull3o<<<gS3, TPB, 0, stream>>>(q4, rp2, ssrc, dinv, b3, out, N);
}

// Round 18
// 206.246 us; speedup vs baseline: 1.0398x; 1.0398x over previous
//
#include <hip/hip_runtime.h>

#define TPB 256
#define NB 391            // ceil(100000/256) coarse buckets of 256 nodes
#define CH 4096           // edges per k_placeA block (391 blocks) -- R16 best
#define BS 4736           // fixed bucket stride (mean 4096 + 10 sigma)

// ---- bf16 helpers (manual RNE pack, shift unpack) ----

__device__ __forceinline__ unsigned bpack(float a, float b) {
    unsigned ua = __float_as_uint(a), ub = __float_as_uint(b);
    ua = (ua + 0x7fffu + ((ua >> 16) & 1u)) >> 16;
    ub = (ub + 0x7fffu + ((ub >> 16) & 1u)) >> 16;
    return ua | (ub << 16);
}
__device__ __forceinline__ float blo(unsigned u) { return __uint_as_float(u << 16); }
__device__ __forceinline__ float bhi(unsigned u) { return __uint_as_float(u & 0xffff0000u); }

// ---------------- chunked coarse bucket sort, LDS-staged grouped writes ----
// packs each edge as  src | ((dst & 255) << 20); dst stashed in LDS so each
// global input word is read exactly once. gcur is ZERO-BASED (memset),
// global slot = b*BS + within-bucket offset.

__global__ __launch_bounds__(TPB) void k_placeA(const int* __restrict__ src,
                                                const int* __restrict__ dst,
                                                unsigned* __restrict__ gcur,
                                                unsigned* __restrict__ bkt, int E) {
    __shared__ unsigned val[CH];
    __shared__ unsigned dstS[CH];
    __shared__ unsigned short bid[CH];
    __shared__ unsigned cnt[512], loff[512], lcur[512], basev[512];
    __shared__ unsigned tsum[TPB];
    int t = threadIdx.x;
    int c0 = blockIdx.x * CH;
    int n = E - c0; if (n > CH) n = CH;

    for (int b = t; b < 512; b += TPB) { cnt[b] = 0; lcur[b] = 0; }
    __syncthreads();
    for (int i = t; i < n; i += TPB) {
        unsigned d = (unsigned)dst[c0 + i];
        dstS[i] = d;
        atomicAdd(&cnt[d >> 8], 1u);
    }
    __syncthreads();
    for (int b = t; b < NB; b += TPB)
        basev[b] = cnt[b] ? atomicAdd(&gcur[b], cnt[b]) : 0u;
    unsigned a0 = cnt[2 * t], a1 = cnt[2 * t + 1];
    tsum[t] = a0 + a1;
    __syncthreads();
#pragma unroll
    for (int o = 1; o < TPB; o <<= 1) {
        unsigned v = (t >= o) ? tsum[t - o] : 0u;
        __syncthreads();
        tsum[t] += v;
        __syncthreads();
    }
    unsigned ex = tsum[t] - (a0 + a1);
    loff[2 * t] = ex; loff[2 * t + 1] = ex + a0;
    __syncthreads();
    for (int i = t; i < n; i += TPB) {
        unsigned s = (unsigned)src[c0 + i];
        unsigned d = dstS[i];
        unsigned b = d >> 8;
        unsigned r = atomicAdd(&lcur[b], 1u);
        unsigned slot = loff[b] + r;
        val[slot] = s | ((d & 255u) << 20);
        bid[slot] = (unsigned short)b;
    }
    __syncthreads();
    for (int i = t; i < n; i += TPB) {
        unsigned b = bid[i];
        bkt[(size_t)b * BS + basev[b] + ((unsigned)i - loff[b])] = val[i];
    }
}

// ---------------- fine sort within bucket -> rp2 + dinv + xs4 + deg hist ---
// 512 threads; key = (dst&255, src>>13): per-node lists sorted by 8k-node
// src chunk (1 MB of gb) -> machine-wide temporal L2 locality. Also builds
// the global degree histogram gdh[64] for the degree permutation.

__global__ __launch_bounds__(512) void k_fineS(const unsigned* __restrict__ bkt,
                                               const unsigned* __restrict__ gcur,
                                               const float* __restrict__ x,
                                               int2* __restrict__ rp2,
                                               int* __restrict__ ssrc,
                                               float* __restrict__ dinv,
                                               float4* __restrict__ xs4,
                                               unsigned* __restrict__ gdh, int N) {
    __shared__ unsigned bins[4096];
    __shared__ unsigned tsum[512];
    __shared__ unsigned degS[256];
    __shared__ unsigned dh[64];
    __shared__ unsigned bs[BS];
    int t = threadIdx.x, b = blockIdx.x;
    for (int i = t; i < 4096; i += 512) bins[i] = 0;
    if (t < 64) dh[t] = 0;
    __syncthreads();
    int p0 = b * BS;
    int n = (int)gcur[b];                     // zero-based count
    for (int i = t; i < n; i += 512) {
        unsigned u = bkt[p0 + i];
        bs[i] = u;
        unsigned bin = ((u >> 20) << 4) | ((u & 0xFFFFFu) >> 13);
        atomicAdd(&bins[bin], 1u);
    }
    __syncthreads();
    // read counts (8 bins/thread) before in-place scan overwrite
    unsigned s[8], pre[8];
#pragma unroll
    for (int i = 0; i < 8; ++i) s[i] = bins[8 * t + i];
    if (t < 256) {
        unsigned d = 0;
#pragma unroll
        for (int i = 0; i < 16; ++i) d += bins[(t << 4) + i];
        degS[t] = d;
    }
    unsigned tot = 0;
#pragma unroll
    for (int i = 0; i < 8; ++i) { pre[i] = tot; tot += s[i]; }
    tsum[t] = tot;
    __syncthreads();
#pragma unroll
    for (int o = 1; o < 512; o <<= 1) {
        unsigned v = (t >= o) ? tsum[t - o] : 0u;
        __syncthreads();
        tsum[t] += v;
        __syncthreads();
    }
    unsigned ex = tsum[t] - tot;
#pragma unroll
    for (int i = 0; i < 8; ++i) bins[8 * t + i] = ex + pre[i];
    __syncthreads();
    if (t < 256) {
        int node = (b << 8) + t;
        if (node < N) {
            unsigned c = degS[t];
            atomicAdd(&dh[c < 63u ? c : 63u], 1u);
            int beg = p0 + (int)bins[t << 4];       // exclusive prefix at node's first bin
            rp2[node] = make_int2(beg, beg + (int)c);
            float dv = rsqrtf((float)(c + 1u));     // +1 = self-loop
            dinv[node] = dv;
            float4 xv;
            xv.x = x[node * 3 + 0] * dv;
            xv.y = x[node * 3 + 1] * dv;
            xv.z = x[node * 3 + 2] * dv;
            xv.w = 0.f;
            xs4[node] = xv;
        }
    }
    __syncthreads();                                // node-beg reads before cursor bumps
    if (t < 64 && dh[t]) atomicAdd(&gdh[t], dh[t]);
    for (int i = t; i < n; i += 512) {
        unsigned u = bs[i];
        unsigned bin = ((u >> 20) << 4) | ((u & 0xFFFFFu) >> 13);
        unsigned r = atomicAdd(&bins[bin], 1u);     // bins now = running cursors
        ssrc[p0 + (int)r] = (int)(u & 0xFFFFFu);
    }
}

// ---------------- degree-bin exclusive scan (1 wave) ----------------

__global__ __launch_bounds__(64) void k_dscan(const unsigned* __restrict__ gdh,
                                              unsigned* __restrict__ dcur) {
    int t = threadIdx.x;
    unsigned v = gdh[t];
    unsigned sum = v;
#pragma unroll
    for (int o = 1; o < 64; o <<= 1) {
        unsigned u = __shfl_up(sum, o, 64);
        if (t >= o) sum += u;
    }
    dcur[t] = sum - v;                              // exclusive base = running cursor
}

// ---------------- degree-binned permutation (counting-sort place) ----------

__global__ __launch_bounds__(TPB) void k_dperm(const int2* __restrict__ rp2,
                                               unsigned* __restrict__ dcur,
                                               int* __restrict__ perm, int N) {
    __shared__ unsigned dh[64], basev[64], lcur[64];
    int t = threadIdx.x;
    int node = blockIdx.x * TPB + t;
    if (t < 64) { dh[t] = 0; lcur[t] = 0; }
    __syncthreads();
    int bin = -1;
    if (node < N) {
        int2 r = rp2[node];
        unsigned d = (unsigned)(r.y - r.x);
        bin = d < 63u ? (int)d : 63;
        atomicAdd(&dh[bin], 1u);
    }
    __syncthreads();
    if (t < 64) basev[t] = dh[t] ? atomicAdd(&dcur[t], dh[t]) : 0u;
    __syncthreads();
    if (node < N) {
        unsigned rk = atomicAdd(&lcur[bin], 1u);
        perm[basev[bin] + rk] = node;
    }
}

// ---------------- fused layer 1 + layer-2 linear (4 lanes/node) ------------
// Nodes taken via degree-sorted perm -> co-wave nodes have equal degree
// (no max-of-16 divergence in the gather loop). lane c aggregates component
// c of xs4; q broadcast in-group; h1 on the fly (scalar W1); 16 output
// features from LDS-staged bf16-packed W2; stores bf16 node-major.

__global__ __launch_bounds__(TPB) void k_l1q(const float* __restrict__ xs4,
                                             const int2* __restrict__ rp2,
                                             const int* __restrict__ ssrc,
                                             const float* __restrict__ dinv,
                                             const int* __restrict__ perm,
                                             const float* __restrict__ W1,
                                             const float* __restrict__ b1,
                                             const float* __restrict__ W2,
                                             uint4* __restrict__ gb, int N) {
    __shared__ unsigned Ws2[2048];                  // W2 as bf16 pairs
    for (int i = threadIdx.x; i < 2048; i += TPB)
        Ws2[i] = bpack(W2[2 * i], W2[2 * i + 1]);
    __syncthreads();                                // before any early return!
    int tid = blockIdx.x * TPB + threadIdx.x;
    int slot = tid >> 2, c = tid & 3;
    if (slot >= N) return;
    int node = perm[slot];                          // broadcast within group
    int2 r = rp2[node];
    float acc = xs4[(node << 2) + c];               // self-loop
    int j = r.x;
    for (; j + 3 < r.y; j += 4) {
        int s0 = ssrc[j], s1 = ssrc[j+1], s2 = ssrc[j+2], s3 = ssrc[j+3];
        acc += (xs4[(s0 << 2) + c] + xs4[(s1 << 2) + c])
             + (xs4[(s2 << 2) + c] + xs4[(s3 << 2) + c]);
    }
    for (; j < r.y; ++j) acc += xs4[(ssrc[j] << 2) + c];
    float dv = dinv[node];
    acc *= dv;
    int base = (threadIdx.x & 63) & ~3;             // my 4-lane group
    float q0 = __shfl(acc, base + 0, 64);
    float q1 = __shfl(acc, base + 1, 64);
    float q2 = __shfl(acc, base + 2, 64);

    float o[16];
#pragma unroll
    for (int i = 0; i < 16; ++i) o[i] = 0.f;
    const int cofs8 = c << 3;                       // 8 u32 per 16 features
    for (int kb = 0; kb < 16; ++kb) {
        int k0 = __builtin_amdgcn_readfirstlane(kb) << 2;
        const float* W1k = W1 + k0;                 // W1[cc*64 + k0+kk]
        const float* b1k = b1 + k0;
        float h[4];
        h[0] = fmaxf(fmaf(q0, W1k[0], fmaf(q1, W1k[64], fmaf(q2, W1k[128], b1k[0]))), 0.f);
        h[1] = fmaxf(fmaf(q0, W1k[1], fmaf(q1, W1k[65], fmaf(q2, W1k[129], b1k[1]))), 0.f);
        h[2] = fmaxf(fmaf(q0, W1k[2], fmaf(q1, W1k[66], fmaf(q2, W1k[130], b1k[2]))), 0.f);
        h[3] = fmaxf(fmaf(q0, W1k[3], fmaf(q1, W1k[67], fmaf(q2, W1k[131], b1k[3]))), 0.f);
#pragma unroll
        for (int kk = 0; kk < 4; ++kk) {
            const uint4* Wp = (const uint4*)(Ws2 + ((k0 + kk) << 5) + cofs8);
            uint4 wA = Wp[0];                       // 4 distinct addrs/wave -> broadcast
            uint4 wB = Wp[1];
            float hv = h[kk];
            o[0]  = fmaf(hv, blo(wA.x), o[0]);  o[1]  = fmaf(hv, bhi(wA.x), o[1]);
            o[2]  = fmaf(hv, blo(wA.y), o[2]);  o[3]  = fmaf(hv, bhi(wA.y), o[3]);
            o[4]  = fmaf(hv, blo(wA.z), o[4]);  o[5]  = fmaf(hv, bhi(wA.z), o[5]);
            o[6]  = fmaf(hv, blo(wA.w), o[6]);  o[7]  = fmaf(hv, bhi(wA.w), o[7]);
            o[8]  = fmaf(hv, blo(wB.x), o[8]);  o[9]  = fmaf(hv, bhi(wB.x), o[9]);
            o[10] = fmaf(hv, blo(wB.y), o[10]); o[11] = fmaf(hv, bhi(wB.y), o[11]);
            o[12] = fmaf(hv, blo(wB.z), o[12]); o[13] = fmaf(hv, bhi(wB.z), o[13]);
            o[14] = fmaf(hv, blo(wB.w), o[14]); o[15] = fmaf(hv, bhi(wB.w), o[15]);
        }
    }
    uint4 v0, v1;
    v0.x = bpack(o[0] * dv,  o[1] * dv);
    v0.y = bpack(o[2] * dv,  o[3] * dv);
    v0.z = bpack(o[4] * dv,  o[5] * dv);
    v0.w = bpack(o[6] * dv,  o[7] * dv);
    v1.x = bpack(o[8] * dv,  o[9] * dv);
    v1.y = bpack(o[10] * dv, o[11] * dv);
    v1.z = bpack(o[12] * dv, o[13] * dv);
    v1.w = bpack(o[14] * dv, o[15] * dv);
    uint4* gp = gb + ((size_t)node << 3) + (c << 1);  // group writes one full 128B line
    gp[0] = v0;
    gp[1] = v1;
}

// ---------------- fused layer-2 pull (bf16) + bias/relu + layer-3 linear ---
// 8 lanes/node via degree-sorted perm (equal-degree waves); 16 B/lane;
// full in-wave W3 reduction. src-chunk-sorted lists -> L2 locality.

__global__ __launch_bounds__(TPB) void k_p2fb(const uint4* __restrict__ gb,
                                              const int2* __restrict__ rp2,
                                              const int* __restrict__ ssrc,
                                              const float* __restrict__ dinv,
                                              const int* __restrict__ perm,
                                              const float* __restrict__ b2,
                                              const float* __restrict__ W3,
                                              float* __restrict__ q4, int N) {
    int tid = blockIdx.x * TPB + threadIdx.x;
    int slot = tid >> 3, q = tid & 7;
    if (slot >= N) return;
    int node = perm[slot];                      // broadcast within group
    int2 r = rp2[node];
    int beg = r.x, end = r.y;
    float a[8];
    {
        uint4 u = gb[((size_t)node << 3) + q];  // self-loop
        a[0] = blo(u.x); a[1] = bhi(u.x);
        a[2] = blo(u.y); a[3] = bhi(u.y);
        a[4] = blo(u.z); a[5] = bhi(u.z);
        a[6] = blo(u.w); a[7] = bhi(u.w);
    }
    int j = beg;
    for (; j + 3 < end; j += 4) {
        int s0 = ssrc[j], s1 = ssrc[j+1], s2 = ssrc[j+2], s3 = ssrc[j+3];
        uint4 u0 = gb[((size_t)s0 << 3) + q];
        uint4 u1 = gb[((size_t)s1 << 3) + q];
        uint4 u2 = gb[((size_t)s2 << 3) + q];
        uint4 u3 = gb[((size_t)s3 << 3) + q];
        a[0] += (blo(u0.x) + blo(u1.x)) + (blo(u2.x) + blo(u3.x));
        a[1] += (bhi(u0.x) + bhi(u1.x)) + (bhi(u2.x) + bhi(u3.x));
        a[2] += (blo(u0.y) + blo(u1.y)) + (blo(u2.y) + blo(u3.y));
        a[3] += (bhi(u0.y) + bhi(u1.y)) + (bhi(u2.y) + bhi(u3.y));
        a[4] += (blo(u0.z) + blo(u1.z)) + (blo(u2.z) + blo(u3.z));
        a[5] += (bhi(u0.z) + bhi(u1.z)) + (bhi(u2.z) + bhi(u3.z));
        a[6] += (blo(u0.w) + blo(u1.w)) + (blo(u2.w) + blo(u3.w));
        a[7] += (bhi(u0.w) + bhi(u1.w)) + (bhi(u2.w) + bhi(u3.w));
    }
    for (; j < end; ++j) {
        uint4 u = gb[((size_t)ssrc[j] << 3) + q];
        a[0] += blo(u.x); a[1] += bhi(u.x);
        a[2] += blo(u.y); a[3] += bhi(u.y);
        a[4] += blo(u.z); a[5] += bhi(u.z);
        a[6] += blo(u.w); a[7] += bhi(u.w);
    }
    float dv = dinv[node];
    int f0 = q << 3;
    const float* bb = b2 + f0;
    const float* Wr = W3 + f0 * 3;              // W3[(f0+i)*3 + c]
    float p0 = 0.f, p1 = 0.f, p2 = 0.f;
#pragma unroll
    for (int i = 0; i < 8; ++i) {
        float h = fmaxf(fmaf(a[i], dv, bb[i]), 0.f);
        p0 = fmaf(h, Wr[3*i+0], p0);
        p1 = fmaf(h, Wr[3*i+1], p1);
        p2 = fmaf(h, Wr[3*i+2], p2);
    }
#pragma unroll
    for (int off = 1; off < 8; off <<= 1) {     // reduce across the 8-lane group
        p0 += __shfl_xor(p0, off, 64);
        p1 += __shfl_xor(p1, off, 64);
        p2 += __shfl_xor(p2, off, 64);
    }
    if (q < 4) {
        float v = (q == 0) ? p0 * dv : (q == 1) ? p1 * dv : (q == 2) ? p2 * dv : 0.f;
        q4[((size_t)node << 2) + q] = v;
    }
}

// ---------------- layer-3 pull with output epilogue (unpermuted) -----------

__global__ __launch_bounds__(TPB) void k_pull3o(const float* __restrict__ g34,
                                                const int2* __restrict__ rp2,
                                                const int* __restrict__ ssrc,
                                                const float* __restrict__ dinv,
                                                const float* __restrict__ b3,
                                                float* __restrict__ out, int N) {
    int tid = blockIdx.x * TPB + threadIdx.x;
    int node = tid >> 2, c = tid & 3;
    if (node >= N) return;
    int2 r = rp2[node];
    int beg = r.x, end = r.y;
    float acc = g34[tid];                       // self-loop
    int j = beg;
    for (; j + 3 < end; j += 4) {
        int s0 = ssrc[j], s1 = ssrc[j+1], s2 = ssrc[j+2], s3 = ssrc[j+3];
        acc += (g34[(s0 << 2) + c] + g34[(s1 << 2) + c])
             + (g34[(s2 << 2) + c] + g34[(s3 << 2) + c]);
    }
    for (; j < end; ++j) acc += g34[(ssrc[j] << 2) + c];
    if (c < 3) out[(size_t)node * 3 + c] = dinv[node] * acc + b3[c];
}

extern "C" void kernel_launch(void* const* d_in, const int* in_sizes, int n_in,
                              void* d_out, int out_size, void* d_ws, size_t ws_size,
                              hipStream_t stream) {
    const float* x  = (const float*)d_in[0];
    const int*   ei = (const int*)  d_in[1];
    const float* W1 = (const float*)d_in[2];
    const float* b1 = (const float*)d_in[3];
    const float* W2 = (const float*)d_in[4];
    const float* b2 = (const float*)d_in[5];
    const float* W3 = (const float*)d_in[6];
    const float* b3 = (const float*)d_in[7];
    float* out = (float*)d_out;

    const int N = in_sizes[0] / 3;       // 100000
    const int E = in_sizes[1] / 2;       // 1600000
    const int* srcI = ei;
    const int* dstI = ei + E;

    // workspace layout (4-byte units), 16B-aligned segments
    float*    ws   = (float*)d_ws;
    unsigned* gcur = (unsigned*)ws;                         // @0        [512]
    unsigned* gdh  = (unsigned*)(ws + 512);                 // @512      [64]
    unsigned* dcur = (unsigned*)(ws + 576);                 // @576      [64]
    int*      perm = (int*)     (ws + 640);                 // [N]
    int2*     rp2  = (int2*)    (ws + 640 + N);             // [N] (2N u32)
    float*    dinv = ws + 640 + 3 * (size_t)N;              // [N]
    int*      ssrc = (int*)     (dinv + N);                 // [NB*BS]
    float*    xs4  = (float*)(ssrc + (size_t)NB * BS);      // [4N]
    float*    q4   = xs4 + (size_t)N * 4;                   // [4N]
    unsigned* gb   = (unsigned*)(q4 + (size_t)N * 4);       // [32N] bf16 g
    unsigned* bkt  = gb + (size_t)N * 32;                   // [NB*BS]

    int gPlace = (E + CH - 1) / CH;                         // 391
    int gS3    = (N * 4 + TPB - 1) / TPB;                   // 1563
    int gP2    = (int)(((size_t)N * 8 + TPB - 1) / TPB);    // 3125
    int gN     = (N + TPB - 1) / TPB;                       // 391

    // preprocessing: fixed-stride bucket sort -> rp2 + dinv + xs4 + deg hist
    hipMemsetAsync(gcur, 0, 576 * sizeof(unsigned), stream);
    k_placeA<<<gPlace, TPB, 0, stream>>>(srcI, dstI, gcur, bkt, E);
    k_fineS <<<NB,     512, 0, stream>>>(bkt, gcur, x, rp2, ssrc, dinv,
                                         (float4*)xs4, gdh, N);
    k_dscan <<<1,       64, 0, stream>>>(gdh, dcur);
    k_dperm <<<gN,     TPB, 0, stream>>>(rp2, dcur, perm, N);

    // layer 1 + layer-2 linear fused (4 lanes/node, degree-sorted)
    k_l1q<<<gS3, TPB, 0, stream>>>(xs4, rp2, ssrc, dinv, perm,
                                   W1, b1, W2, (uint4*)gb, N);

    // layer-2 pull (bf16, degree-sorted) + bias/relu + layer-3 linear fused
    k_p2fb<<<gP2, TPB, 0, stream>>>((const uint4*)gb, rp2, ssrc, dinv, perm,
                                    b2, W3, q4, N);

    // layer-3 pull (+bias fused)
    k_pull3o<<<gS3, TPB, 0, stream>>>(q4, rp2, ssrc, dinv, b3, out, N);
}

// Round 19
// 203.954 us; speedup vs baseline: 1.0515x; 1.0112x over previous
//
#include <hip/hip_runtime.h>

#define TPB 256
#define NB 391            // ceil(100000/256) coarse buckets of 256 nodes
#define CH 4096           // edges per k_placeA block (391 blocks)
#define BS 4736           // fixed bucket stride (mean 4096 + 10 sigma)

// ---- bf16 helpers (manual RNE pack, shift unpack) ----

__device__ __forceinline__ unsigned bpack(float a, float b) {
    unsigned ua = __float_as_uint(a), ub = __float_as_uint(b);
    ua = (ua + 0x7fffu + ((ua >> 16) & 1u)) >> 16;
    ub = (ub + 0x7fffu + ((ub >> 16) & 1u)) >> 16;
    return ua | (ub << 16);
}
__device__ __forceinline__ float blo(unsigned u) { return __uint_as_float(u << 16); }
__device__ __forceinline__ float bhi(unsigned u) { return __uint_as_float(u & 0xffff0000u); }

// ---------------- chunked coarse bucket sort, LDS-staged grouped writes ----
// packs each edge as  src | ((dst & 255) << 20); dst stashed in LDS so each
// global input word is read exactly once. gcur is ZERO-BASED (memset),
// global slot = b*BS + within-bucket offset.

__global__ __launch_bounds__(TPB) void k_placeA(const int* __restrict__ src,
                                                const int* __restrict__ dst,
                                                unsigned* __restrict__ gcur,
                                                unsigned* __restrict__ bkt, int E) {
    __shared__ unsigned val[CH];
    __shared__ unsigned dstS[CH];
    __shared__ unsigned short bid[CH];
    __shared__ unsigned cnt[512], loff[512], lcur[512], basev[512];
    __shared__ unsigned tsum[TPB];
    int t = threadIdx.x;
    int c0 = blockIdx.x * CH;
    int n = E - c0; if (n > CH) n = CH;

    for (int b = t; b < 512; b += TPB) { cnt[b] = 0; lcur[b] = 0; }
    __syncthreads();
    for (int i = t; i < n; i += TPB) {
        unsigned d = (unsigned)dst[c0 + i];
        dstS[i] = d;
        atomicAdd(&cnt[d >> 8], 1u);
    }
    __syncthreads();
    for (int b = t; b < NB; b += TPB)
        basev[b] = cnt[b] ? atomicAdd(&gcur[b], cnt[b]) : 0u;
    unsigned a0 = cnt[2 * t], a1 = cnt[2 * t + 1];
    tsum[t] = a0 + a1;
    __syncthreads();
#pragma unroll
    for (int o = 1; o < TPB; o <<= 1) {
        unsigned v = (t >= o) ? tsum[t - o] : 0u;
        __syncthreads();
        tsum[t] += v;
        __syncthreads();
    }
    unsigned ex = tsum[t] - (a0 + a1);
    loff[2 * t] = ex; loff[2 * t + 1] = ex + a0;
    __syncthreads();
    for (int i = t; i < n; i += TPB) {
        unsigned s = (unsigned)src[c0 + i];
        unsigned d = dstS[i];
        unsigned b = d >> 8;
        unsigned r = atomicAdd(&lcur[b], 1u);
        unsigned slot = loff[b] + r;
        val[slot] = s | ((d & 255u) << 20);
        bid[slot] = (unsigned short)b;
    }
    __syncthreads();
    for (int i = t; i < n; i += TPB) {
        unsigned b = bid[i];
        bkt[(size_t)b * BS + basev[b] + ((unsigned)i - loff[b])] = val[i];
    }
}

// ---------------- fine sort within bucket -> rp2 + dinv + xs4 + deg hist ---
// 512 threads; key = (dst&255, src>>13): per-node lists sorted by 8k-node
// src chunk (1 MB of gb) -> machine-wide temporal L2 locality. Also builds
// the global degree histogram gdh[64] for the degree permutation.

__global__ __launch_bounds__(512) void k_fineS(const unsigned* __restrict__ bkt,
                                               const unsigned* __restrict__ gcur,
                                               const float* __restrict__ x,
                                               int2* __restrict__ rp2,
                                               int* __restrict__ ssrc,
                                               float* __restrict__ dinv,
                                               float4* __restrict__ xs4,
                                               unsigned* __restrict__ gdh, int N) {
    __shared__ unsigned bins[4096];
    __shared__ unsigned tsum[512];
    __shared__ unsigned degS[256];
    __shared__ unsigned dh[64];
    __shared__ unsigned bs[BS];
    int t = threadIdx.x, b = blockIdx.x;
    for (int i = t; i < 4096; i += 512) bins[i] = 0;
    if (t < 64) dh[t] = 0;
    __syncthreads();
    int p0 = b * BS;
    int n = (int)gcur[b];                     // zero-based count
    for (int i = t; i < n; i += 512) {
        unsigned u = bkt[p0 + i];
        bs[i] = u;
        unsigned bin = ((u >> 20) << 4) | ((u & 0xFFFFFu) >> 13);
        atomicAdd(&bins[bin], 1u);
    }
    __syncthreads();
    // read counts (8 bins/thread) before in-place scan overwrite
    unsigned s[8], pre[8];
#pragma unroll
    for (int i = 0; i < 8; ++i) s[i] = bins[8 * t + i];
    if (t < 256) {
        unsigned d = 0;
#pragma unroll
        for (int i = 0; i < 16; ++i) d += bins[(t << 4) + i];
        degS[t] = d;
    }
    unsigned tot = 0;
#pragma unroll
    for (int i = 0; i < 8; ++i) { pre[i] = tot; tot += s[i]; }
    tsum[t] = tot;
    __syncthreads();
#pragma unroll
    for (int o = 1; o < 512; o <<= 1) {
        unsigned v = (t >= o) ? tsum[t - o] : 0u;
        __syncthreads();
        tsum[t] += v;
        __syncthreads();
    }
    unsigned ex = tsum[t] - tot;
#pragma unroll
    for (int i = 0; i < 8; ++i) bins[8 * t + i] = ex + pre[i];
    __syncthreads();
    if (t < 256) {
        int node = (b << 8) + t;
        if (node < N) {
            unsigned c = degS[t];
            atomicAdd(&dh[c < 63u ? c : 63u], 1u);
            int beg = p0 + (int)bins[t << 4];       // exclusive prefix at node's first bin
            rp2[node] = make_int2(beg, beg + (int)c);
            float dv = rsqrtf((float)(c + 1u));     // +1 = self-loop
            dinv[node] = dv;
            float4 xv;
            xv.x = x[node * 3 + 0] * dv;
            xv.y = x[node * 3 + 1] * dv;
            xv.z = x[node * 3 + 2] * dv;
            xv.w = 0.f;
            xs4[node] = xv;
        }
    }
    __syncthreads();                                // node-beg reads before cursor bumps
    if (t < 64 && dh[t]) atomicAdd(&gdh[t], dh[t]);
    for (int i = t; i < n; i += 512) {
        unsigned u = bs[i];
        unsigned bin = ((u >> 20) << 4) | ((u & 0xFFFFFu) >> 13);
        unsigned r = atomicAdd(&bins[bin], 1u);     // bins now = running cursors
        ssrc[p0 + (int)r] = (int)(u & 0xFFFFFu);
    }
}

// ---------------- degree-bin suffix scan (1 wave) -> DESCENDING placement --
// base[t] = sum of gdh[t'] for t' > t: highest-degree nodes get the lowest
// slots, so heavy blocks launch FIRST (LPT scheduling, no drain tail).

__global__ __launch_bounds__(64) void k_dscan(const unsigned* __restrict__ gdh,
                                              unsigned* __restrict__ dcur) {
    int t = threadIdx.x;
    unsigned v = gdh[t];
    unsigned sum = v;                               // inclusive prefix
#pragma unroll
    for (int o = 1; o < 64; o <<= 1) {
        unsigned u = __shfl_up(sum, o, 64);
        if (t >= o) sum += u;
    }
    unsigned total = __shfl(sum, 63, 64);
    dcur[t] = total - sum;                          // suffix sum (bins > t)
}

// ---------------- degree-binned permutation (counting-sort place) ----------

__global__ __launch_bounds__(TPB) void k_dperm(const int2* __restrict__ rp2,
                                               unsigned* __restrict__ dcur,
                                               int* __restrict__ perm, int N) {
    __shared__ unsigned dh[64], basev[64], lcur[64];
    int t = threadIdx.x;
    int node = blockIdx.x * TPB + t;
    if (t < 64) { dh[t] = 0; lcur[t] = 0; }
    __syncthreads();
    int bin = -1;
    if (node < N) {
        int2 r = rp2[node];
        unsigned d = (unsigned)(r.y - r.x);
        bin = d < 63u ? (int)d : 63;
        atomicAdd(&dh[bin], 1u);
    }
    __syncthreads();
    if (t < 64) basev[t] = dh[t] ? atomicAdd(&dcur[t], dh[t]) : 0u;
    __syncthreads();
    if (node < N) {
        unsigned rk = atomicAdd(&lcur[bin], 1u);
        perm[basev[bin] + rk] = node;
    }
}

// ---------------- fused layer 1 + layer-2 linear (4 lanes/node) ------------
// Nodes taken via degree-sorted perm (descending: heavy blocks first).
// lane c aggregates component c of xs4; q broadcast in-group; h1 on the fly
// (scalar W1); 16 output features from LDS-staged bf16-packed W2; bf16 store.

__global__ __launch_bounds__(TPB) void k_l1q(const float* __restrict__ xs4,
                                             const int2* __restrict__ rp2,
                                             const int* __restrict__ ssrc,
                                             const float* __restrict__ dinv,
                                             const int* __restrict__ perm,
                                             const float* __restrict__ W1,
                                             const float* __restrict__ b1,
                                             const float* __restrict__ W2,
                                             uint4* __restrict__ gb, int N) {
    __shared__ unsigned Ws2[2048];                  // W2 as bf16 pairs
    for (int i = threadIdx.x; i < 2048; i += TPB)
        Ws2[i] = bpack(W2[2 * i], W2[2 * i + 1]);
    __syncthreads();                                // before any early return!
    int tid = blockIdx.x * TPB + threadIdx.x;
    int slot = tid >> 2, c = tid & 3;
    if (slot >= N) return;
    int node = perm[slot];                          // broadcast within group
    int2 r = rp2[node];
    float acc = xs4[(node << 2) + c];               // self-loop
    int j = r.x;
    for (; j + 3 < r.y; j += 4) {
        int s0 = ssrc[j], s1 = ssrc[j+1], s2 = ssrc[j+2], s3 = ssrc[j+3];
        acc += (xs4[(s0 << 2) + c] + xs4[(s1 << 2) + c])
             + (xs4[(s2 << 2) + c] + xs4[(s3 << 2) + c]);
    }
    for (; j < r.y; ++j) acc += xs4[(ssrc[j] << 2) + c];
    float dv = dinv[node];
    acc *= dv;
    int base = (threadIdx.x & 63) & ~3;             // my 4-lane group
    float q0 = __shfl(acc, base + 0, 64);
    float q1 = __shfl(acc, base + 1, 64);
    float q2 = __shfl(acc, base + 2, 64);

    float o[16];
#pragma unroll
    for (int i = 0; i < 16; ++i) o[i] = 0.f;
    const int cofs8 = c << 3;                       // 8 u32 per 16 features
    for (int kb = 0; kb < 16; ++kb) {
        int k0 = __builtin_amdgcn_readfirstlane(kb) << 2;
        const float* W1k = W1 + k0;                 // W1[cc*64 + k0+kk]
        const float* b1k = b1 + k0;
        float h[4];
        h[0] = fmaxf(fmaf(q0, W1k[0], fmaf(q1, W1k[64], fmaf(q2, W1k[128], b1k[0]))), 0.f);
        h[1] = fmaxf(fmaf(q0, W1k[1], fmaf(q1, W1k[65], fmaf(q2, W1k[129], b1k[1]))), 0.f);
        h[2] = fmaxf(fmaf(q0, W1k[2], fmaf(q1, W1k[66], fmaf(q2, W1k[130], b1k[2]))), 0.f);
        h[3] = fmaxf(fmaf(q0, W1k[3], fmaf(q1, W1k[67], fmaf(q2, W1k[131], b1k[3]))), 0.f);
#pragma unroll
        for (int kk = 0; kk < 4; ++kk) {
            const uint4* Wp = (const uint4*)(Ws2 + ((k0 + kk) << 5) + cofs8);
            uint4 wA = Wp[0];                       // 4 distinct addrs/wave -> broadcast
            uint4 wB = Wp[1];
            float hv = h[kk];
            o[0]  = fmaf(hv, blo(wA.x), o[0]);  o[1]  = fmaf(hv, bhi(wA.x), o[1]);
            o[2]  = fmaf(hv, blo(wA.y), o[2]);  o[3]  = fmaf(hv, bhi(wA.y), o[3]);
            o[4]  = fmaf(hv, blo(wA.z), o[4]);  o[5]  = fmaf(hv, bhi(wA.z), o[5]);
            o[6]  = fmaf(hv, blo(wA.w), o[6]);  o[7]  = fmaf(hv, bhi(wA.w), o[7]);
            o[8]  = fmaf(hv, blo(wB.x), o[8]);  o[9]  = fmaf(hv, bhi(wB.x), o[9]);
            o[10] = fmaf(hv, blo(wB.y), o[10]); o[11] = fmaf(hv, bhi(wB.y), o[11]);
            o[12] = fmaf(hv, blo(wB.z), o[12]); o[13] = fmaf(hv, bhi(wB.z), o[13]);
            o[14] = fmaf(hv, blo(wB.w), o[14]); o[15] = fmaf(hv, bhi(wB.w), o[15]);
        }
    }
    uint4 v0, v1;
    v0.x = bpack(o[0] * dv,  o[1] * dv);
    v0.y = bpack(o[2] * dv,  o[3] * dv);
    v0.z = bpack(o[4] * dv,  o[5] * dv);
    v0.w = bpack(o[6] * dv,  o[7] * dv);
    v1.x = bpack(o[8] * dv,  o[9] * dv);
    v1.y = bpack(o[10] * dv, o[11] * dv);
    v1.z = bpack(o[12] * dv, o[13] * dv);
    v1.w = bpack(o[14] * dv, o[15] * dv);
    uint4* gp = gb + ((size_t)node << 3) + (c << 1);  // group writes one full 128B line
    gp[0] = v0;
    gp[1] = v1;
}

// ---------------- fused layer-2 pull (bf16) + bias/relu + layer-3 linear ---
// 8 lanes/node via degree-sorted perm (descending); 16 B/lane; full in-wave
// W3 reduction. src-chunk-sorted lists -> L2 locality.

__global__ __launch_bounds__(TPB) void k_p2fb(const uint4* __restrict__ gb,
                                              const int2* __restrict__ rp2,
                                              const int* __restrict__ ssrc,
                                              const float* __restrict__ dinv,
                                              const int* __restrict__ perm,
                                              const float* __restrict__ b2,
                                              const float* __restrict__ W3,
                                              float* __restrict__ q4, int N) {
    int tid = blockIdx.x * TPB + threadIdx.x;
    int slot = tid >> 3, q = tid & 7;
    if (slot >= N) return;
    int node = perm[slot];                      // broadcast within group
    int2 r = rp2[node];
    int beg = r.x, end = r.y;
    float a[8];
    {
        uint4 u = gb[((size_t)node << 3) + q];  // self-loop
        a[0] = blo(u.x); a[1] = bhi(u.x);
        a[2] = blo(u.y); a[3] = bhi(u.y);
        a[4] = blo(u.z); a[5] = bhi(u.z);
        a[6] = blo(u.w); a[7] = bhi(u.w);
    }
    int j = beg;
    for (; j + 3 < end; j += 4) {
        int s0 = ssrc[j], s1 = ssrc[j+1], s2 = ssrc[j+2], s3 = ssrc[j+3];
        uint4 u0 = gb[((size_t)s0 << 3) + q];
        uint4 u1 = gb[((size_t)s1 << 3) + q];
        uint4 u2 = gb[((size_t)s2 << 3) + q];
        uint4 u3 = gb[((size_t)s3 << 3) + q];
        a[0] += (blo(u0.x) + blo(u1.x)) + (blo(u2.x) + blo(u3.x));
        a[1] += (bhi(u0.x) + bhi(u1.x)) + (bhi(u2.x) + bhi(u3.x));
        a[2] += (blo(u0.y) + blo(u1.y)) + (blo(u2.y) + blo(u3.y));
        a[3] += (bhi(u0.y) + bhi(u1.y)) + (bhi(u2.y) + bhi(u3.y));
        a[4] += (blo(u0.z) + blo(u1.z)) + (blo(u2.z) + blo(u3.z));
        a[5] += (bhi(u0.z) + bhi(u1.z)) + (bhi(u2.z) + bhi(u3.z));
        a[6] += (blo(u0.w) + blo(u1.w)) + (blo(u2.w) + blo(u3.w));
        a[7] += (bhi(u0.w) + bhi(u1.w)) + (bhi(u2.w) + bhi(u3.w));
    }
    for (; j < end; ++j) {
        uint4 u = gb[((size_t)ssrc[j] << 3) + q];
        a[0] += blo(u.x); a[1] += bhi(u.x);
        a[2] += blo(u.y); a[3] += bhi(u.y);
        a[4] += blo(u.z); a[5] += bhi(u.z);
        a[6] += blo(u.w); a[7] += bhi(u.w);
    }
    float dv = dinv[node];
    int f0 = q << 3;
    const float* bb = b2 + f0;
    const float* Wr = W3 + f0 * 3;              // W3[(f0+i)*3 + c]
    float p0 = 0.f, p1 = 0.f, p2 = 0.f;
#pragma unroll
    for (int i = 0; i < 8; ++i) {
        float h = fmaxf(fmaf(a[i], dv, bb[i]), 0.f);
        p0 = fmaf(h, Wr[3*i+0], p0);
        p1 = fmaf(h, Wr[3*i+1], p1);
        p2 = fmaf(h, Wr[3*i+2], p2);
    }
#pragma unroll
    for (int off = 1; off < 8; off <<= 1) {     // reduce across the 8-lane group
        p0 += __shfl_xor(p0, off, 64);
        p1 += __shfl_xor(p1, off, 64);
        p2 += __shfl_xor(p2, off, 64);
    }
    if (q < 4) {
        float v = (q == 0) ? p0 * dv : (q == 1) ? p1 * dv : (q == 2) ? p2 * dv : 0.f;
        q4[((size_t)node << 2) + q] = v;
    }
}

// ---------------- layer-3 pull with output epilogue (unpermuted) -----------

__global__ __launch_bounds__(TPB) void k_pull3o(const float* __restrict__ g34,
                                                const int2* __restrict__ rp2,
                                                const int* __restrict__ ssrc,
                                                const float* __restrict__ dinv,
                                                const float* __restrict__ b3,
                                                float* __restrict__ out, int N) {
    int tid = blockIdx.x * TPB + threadIdx.x;
    int node = tid >> 2, c = tid & 3;
    if (node >= N) return;
    int2 r = rp2[node];
    int beg = r.x, end = r.y;
    float acc = g34[tid];                       // self-loop
    int j = beg;
    for (; j + 3 < end; j += 4) {
        int s0 = ssrc[j], s1 = ssrc[j+1], s2 = ssrc[j+2], s3 = ssrc[j+3];
        acc += (g34[(s0 << 2) + c] + g34[(s1 << 2) + c])
             + (g34[(s2 << 2) + c] + g34[(s3 << 2) + c]);
    }
    for (; j < end; ++j) acc += g34[(ssrc[j] << 2) + c];
    if (c < 3) out[(size_t)node * 3 + c] = dinv[node] * acc + b3[c];
}

extern "C" void kernel_launch(void* const* d_in, const int* in_sizes, int n_in,
                              void* d_out, int out_size, void* d_ws, size_t ws_size,
                              hipStream_t stream) {
    const float* x  = (const float*)d_in[0];
    const int*   ei = (const int*)  d_in[1];
    const float* W1 = (const float*)d_in[2];
    const float* b1 = (const float*)d_in[3];
    const float* W2 = (const float*)d_in[4];
    const float* b2 = (const float*)d_in[5];
    const float* W3 = (const float*)d_in[6];
    const float* b3 = (const float*)d_in[7];
    float* out = (float*)d_out;

    const int N = in_sizes[0] / 3;       // 100000
    const int E = in_sizes[1] / 2;       // 1600000
    const int* srcI = ei;
    const int* dstI = ei + E;

    // workspace layout (4-byte units), 16B-aligned segments
    float*    ws   = (float*)d_ws;
    unsigned* gcur = (unsigned*)ws;                         // @0        [512]
    unsigned* gdh  = (unsigned*)(ws + 512);                 // @512      [64]
    unsigned* dcur = (unsigned*)(ws + 576);                 // @576      [64]
    int*      perm = (int*)     (ws + 640);                 // [N]
    int2*     rp2  = (int2*)    (ws + 640 + N);             // [N] (2N u32)
    float*    dinv = ws + 640 + 3 * (size_t)N;              // [N]
    int*      ssrc = (int*)     (dinv + N);                 // [NB*BS]
    float*    xs4  = (float*)(ssrc + (size_t)NB * BS);      // [4N]
    float*    q4   = xs4 + (size_t)N * 4;                   // [4N]
    unsigned* gb   = (unsigned*)(q4 + (size_t)N * 4);       // [32N] bf16 g
    unsigned* bkt  = gb + (size_t)N * 32;                   // [NB*BS]

    int gPlace = (E + CH - 1) / CH;                         // 391
    int gS3    = (N * 4 + TPB - 1) / TPB;                   // 1563
    int gP2    = (int)(((size_t)N * 8 + TPB - 1) / TPB);    // 3125
    int gN     = (N + TPB - 1) / TPB;                       // 391

    // preprocessing: fixed-stride bucket sort -> rp2 + dinv + xs4 + deg hist
    hipMemsetAsync(gcur, 0, 576 * sizeof(unsigned), stream);
    k_placeA<<<gPlace, TPB, 0, stream>>>(srcI, dstI, gcur, bkt, E);
    k_fineS <<<NB,     512, 0, stream>>>(bkt, gcur, x, rp2, ssrc, dinv,
                                         (float4*)xs4, gdh, N);
    k_dscan <<<1,       64, 0, stream>>>(gdh, dcur);
    k_dperm <<<gN,     TPB, 0, stream>>>(rp2, dcur, perm, N);

    // layer 1 + layer-2 linear fused (4 lanes/node, degree-desc perm)
    k_l1q<<<gS3, TPB, 0, stream>>>(xs4, rp2, ssrc, dinv, perm,
                                   W1, b1, W2, (uint4*)gb, N);

    // layer-2 pull (bf16, degree-desc perm) + bias/relu + layer-3 linear
    k_p2fb<<<gP2, TPB, 0, stream>>>((const uint4*)gb, rp2, ssrc, dinv, perm,
                                    b2, W3, q4, N);

    // layer-3 pull (+bias fused)
    k_pull3o<<<gS3, TPB, 0, stream>>>(q4, rp2, ssrc, dinv, b3, out, N);
}

// Round 20
// 200.879 us; speedup vs baseline: 1.0676x; 1.0153x over previous
//
#include <hip/hip_runtime.h>

#define TPB 256
#define NB 391            // ceil(100000/256) coarse buckets of 256 nodes
#define CH 4096           // edges per k_placeA block (391 blocks)
#define BS 4736           // fixed bucket stride (mean 4096 + 10 sigma)

// ---- bf16 helpers (manual RNE pack, shift unpack) ----

__device__ __forceinline__ unsigned bpack(float a, float b) {
    unsigned ua = __float_as_uint(a), ub = __float_as_uint(b);
    ua = (ua + 0x7fffu + ((ua >> 16) & 1u)) >> 16;
    ub = (ub + 0x7fffu + ((ub >> 16) & 1u)) >> 16;
    return ua | (ub << 16);
}
__device__ __forceinline__ float blo(unsigned u) { return __uint_as_float(u << 16); }
__device__ __forceinline__ float bhi(unsigned u) { return __uint_as_float(u & 0xffff0000u); }

// ---------------- chunked coarse bucket sort, LDS-staged grouped writes ----

__global__ __launch_bounds__(TPB) void k_placeA(const int* __restrict__ src,
                                                const int* __restrict__ dst,
                                                unsigned* __restrict__ gcur,
                                                unsigned* __restrict__ bkt, int E) {
    __shared__ unsigned val[CH];
    __shared__ unsigned dstS[CH];
    __shared__ unsigned short bid[CH];
    __shared__ unsigned cnt[512], loff[512], lcur[512], basev[512];
    __shared__ unsigned tsum[TPB];
    int t = threadIdx.x;
    int c0 = blockIdx.x * CH;
    int n = E - c0; if (n > CH) n = CH;

    for (int b = t; b < 512; b += TPB) { cnt[b] = 0; lcur[b] = 0; }
    __syncthreads();
    for (int i = t; i < n; i += TPB) {
        unsigned d = (unsigned)dst[c0 + i];
        dstS[i] = d;
        atomicAdd(&cnt[d >> 8], 1u);
    }
    __syncthreads();
    for (int b = t; b < NB; b += TPB)
        basev[b] = cnt[b] ? atomicAdd(&gcur[b], cnt[b]) : 0u;
    unsigned a0 = cnt[2 * t], a1 = cnt[2 * t + 1];
    tsum[t] = a0 + a1;
    __syncthreads();
#pragma unroll
    for (int o = 1; o < TPB; o <<= 1) {
        unsigned v = (t >= o) ? tsum[t - o] : 0u;
        __syncthreads();
        tsum[t] += v;
        __syncthreads();
    }
    unsigned ex = tsum[t] - (a0 + a1);
    loff[2 * t] = ex; loff[2 * t + 1] = ex + a0;
    __syncthreads();
    for (int i = t; i < n; i += TPB) {
        unsigned s = (unsigned)src[c0 + i];
        unsigned d = dstS[i];
        unsigned b = d >> 8;
        unsigned r = atomicAdd(&lcur[b], 1u);
        unsigned slot = loff[b] + r;
        val[slot] = s | ((d & 255u) << 20);
        bid[slot] = (unsigned short)b;
    }
    __syncthreads();
    for (int i = t; i < n; i += TPB) {
        unsigned b = bid[i];
        bkt[(size_t)b * BS + basev[b] + ((unsigned)i - loff[b])] = val[i];
    }
}

// ---------------- fine sort within bucket -> rp2 + dinv + xs4 + deg hist ---

__global__ __launch_bounds__(512) void k_fineS(const unsigned* __restrict__ bkt,
                                               const unsigned* __restrict__ gcur,
                                               const float* __restrict__ x,
                                               int2* __restrict__ rp2,
                                               int* __restrict__ ssrc,
                                               float* __restrict__ dinv,
                                               float4* __restrict__ xs4,
                                               unsigned* __restrict__ gdh, int N) {
    __shared__ unsigned bins[4096];
    __shared__ unsigned tsum[512];
    __shared__ unsigned degS[256];
    __shared__ unsigned dh[64];
    __shared__ unsigned bs[BS];
    int t = threadIdx.x, b = blockIdx.x;
    for (int i = t; i < 4096; i += 512) bins[i] = 0;
    if (t < 64) dh[t] = 0;
    __syncthreads();
    int p0 = b * BS;
    int n = (int)gcur[b];                     // zero-based count
    for (int i = t; i < n; i += 512) {
        unsigned u = bkt[p0 + i];
        bs[i] = u;
        unsigned bin = ((u >> 20) << 4) | ((u & 0xFFFFFu) >> 13);
        atomicAdd(&bins[bin], 1u);
    }
    __syncthreads();
    unsigned s[8], pre[8];
#pragma unroll
    for (int i = 0; i < 8; ++i) s[i] = bins[8 * t + i];
    if (t < 256) {
        unsigned d = 0;
#pragma unroll
        for (int i = 0; i < 16; ++i) d += bins[(t << 4) + i];
        degS[t] = d;
    }
    unsigned tot = 0;
#pragma unroll
    for (int i = 0; i < 8; ++i) { pre[i] = tot; tot += s[i]; }
    tsum[t] = tot;
    __syncthreads();
#pragma unroll
    for (int o = 1; o < 512; o <<= 1) {
        unsigned v = (t >= o) ? tsum[t - o] : 0u;
        __syncthreads();
        tsum[t] += v;
        __syncthreads();
    }
    unsigned ex = tsum[t] - tot;
#pragma unroll
    for (int i = 0; i < 8; ++i) bins[8 * t + i] = ex + pre[i];
    __syncthreads();
    if (t < 256) {
        int node = (b << 8) + t;
        if (node < N) {
            unsigned c = degS[t];
            atomicAdd(&dh[c < 63u ? c : 63u], 1u);
            int beg = p0 + (int)bins[t << 4];
            rp2[node] = make_int2(beg, beg + (int)c);
            float dv = rsqrtf((float)(c + 1u));     // +1 = self-loop
            dinv[node] = dv;
            float4 xv;
            xv.x = x[node * 3 + 0] * dv;
            xv.y = x[node * 3 + 1] * dv;
            xv.z = x[node * 3 + 2] * dv;
            xv.w = 0.f;
            xs4[node] = xv;
        }
    }
    __syncthreads();
    if (t < 64 && dh[t]) atomicAdd(&gdh[t], dh[t]);
    for (int i = t; i < n; i += 512) {
        unsigned u = bs[i];
        unsigned bin = ((u >> 20) << 4) | ((u & 0xFFFFFu) >> 13);
        unsigned r = atomicAdd(&bins[bin], 1u);
        ssrc[p0 + (int)r] = (int)(u & 0xFFFFFu);
    }
}

// ---------------- degree-bin suffix scan (descending / LPT) ----------------

__global__ __launch_bounds__(64) void k_dscan(const unsigned* __restrict__ gdh,
                                              unsigned* __restrict__ dcur) {
    int t = threadIdx.x;
    unsigned v = gdh[t];
    unsigned sum = v;
#pragma unroll
    for (int o = 1; o < 64; o <<= 1) {
        unsigned u = __shfl_up(sum, o, 64);
        if (t >= o) sum += u;
    }
    unsigned total = __shfl(sum, 63, 64);
    dcur[t] = total - sum;                          // suffix sum (bins > t)
}

// ---------------- degree-binned permutation (counting-sort place) ----------

__global__ __launch_bounds__(TPB) void k_dperm(const int2* __restrict__ rp2,
                                               unsigned* __restrict__ dcur,
                                               int* __restrict__ perm, int N) {
    __shared__ unsigned dh[64], basev[64], lcur[64];
    int t = threadIdx.x;
    int node = blockIdx.x * TPB + t;
    if (t < 64) { dh[t] = 0; lcur[t] = 0; }
    __syncthreads();
    int bin = -1;
    if (node < N) {
        int2 r = rp2[node];
        unsigned d = (unsigned)(r.y - r.x);
        bin = d < 63u ? (int)d : 63;
        atomicAdd(&dh[bin], 1u);
    }
    __syncthreads();
    if (t < 64) basev[t] = dh[t] ? atomicAdd(&dcur[t], dh[t]) : 0u;
    __syncthreads();
    if (node < N) {
        unsigned rk = atomicAdd(&lcur[bin], 1u);
        perm[basev[bin] + rk] = node;
    }
}

// ---------------- layer-1 gather (4 lanes/node, natural order) -------------
// qx4[node] = (q0*dv, q1*dv, q2*dv, dv); coalesced ssrc/xs4/rp2 streams.

__global__ __launch_bounds__(TPB) void k_gq(const float* __restrict__ xs4,
                                            const int2* __restrict__ rp2,
                                            const int* __restrict__ ssrc,
                                            const float* __restrict__ dinv,
                                            float* __restrict__ qx4, int N) {
    int tid = blockIdx.x * TPB + threadIdx.x;
    int node = tid >> 2, c = tid & 3;
    if (node >= N) return;
    int2 r = rp2[node];
    float acc = xs4[tid];                       // self-loop (c=3 lane carries 0)
    int j = r.x;
    for (; j + 3 < r.y; j += 4) {
        int s0 = ssrc[j], s1 = ssrc[j+1], s2 = ssrc[j+2], s3 = ssrc[j+3];
        acc += (xs4[(s0 << 2) + c] + xs4[(s1 << 2) + c])
             + (xs4[(s2 << 2) + c] + xs4[(s3 << 2) + c]);
    }
    for (; j < r.y; ++j) acc += xs4[(ssrc[j] << 2) + c];
    float dv = dinv[node];
    qx4[tid] = (c < 3) ? acc * dv : dv;
}

// ---------------- layer-1+2 dense (thread = node x feature-half) -----------
// half = t>>7 is WAVE-UNIFORM -> W2 rows via s_load (scalar pipe, f32, zero
// LDS). o[32] per thread; h1 recomputed per half (cheap). bf16 store matches
// k_p2fb's gb layout.

__global__ __launch_bounds__(TPB) void k_l1d(const float4* __restrict__ qx4,
                                             const float* __restrict__ W1,
                                             const float* __restrict__ b1,
                                             const float* __restrict__ W2,
                                             uint4* __restrict__ gb, int N) {
    int t = threadIdx.x;
    int node = blockIdx.x * 128 + (t & 127);
    int half = __builtin_amdgcn_readfirstlane(t >> 7);
    if (node >= N) return;
    float4 qv = qx4[node];
    float q0 = qv.x, q1 = qv.y, q2 = qv.z, dv = qv.w;
    float o[32];
#pragma unroll
    for (int i = 0; i < 32; ++i) o[i] = 0.f;
    const int fofs = half << 5;
    for (int kb = 0; kb < 16; ++kb) {
        int k0 = __builtin_amdgcn_readfirstlane(kb) << 2;
        const float* W1k = W1 + k0;             // scalar path
        const float* b1k = b1 + k0;
        float h[4];
        h[0] = fmaxf(fmaf(q0, W1k[0], fmaf(q1, W1k[64], fmaf(q2, W1k[128], b1k[0]))), 0.f);
        h[1] = fmaxf(fmaf(q0, W1k[1], fmaf(q1, W1k[65], fmaf(q2, W1k[129], b1k[1]))), 0.f);
        h[2] = fmaxf(fmaf(q0, W1k[2], fmaf(q1, W1k[66], fmaf(q2, W1k[130], b1k[2]))), 0.f);
        h[3] = fmaxf(fmaf(q0, W1k[3], fmaf(q1, W1k[67], fmaf(q2, W1k[131], b1k[3]))), 0.f);
#pragma unroll
        for (int kk = 0; kk < 4; ++kk) {
            const float* Wr = W2 + ((k0 + kk) << 6) + fofs;   // uniform -> s_load
            float hv = h[kk];
#pragma unroll
            for (int i = 0; i < 32; ++i)
                o[i] = fmaf(hv, Wr[i], o[i]);
        }
    }
    uint4* gp = gb + ((size_t)node << 3) + (half << 2);
#pragma unroll
    for (int g8 = 0; g8 < 4; ++g8) {
        uint4 v;
        v.x = bpack(o[8*g8+0] * dv, o[8*g8+1] * dv);
        v.y = bpack(o[8*g8+2] * dv, o[8*g8+3] * dv);
        v.z = bpack(o[8*g8+4] * dv, o[8*g8+5] * dv);
        v.w = bpack(o[8*g8+6] * dv, o[8*g8+7] * dv);
        gp[g8] = v;
    }
}

// ---------------- fused layer-2 pull (bf16) + bias/relu + layer-3 linear ---
// 8 lanes/node via degree-desc perm; 16 B/lane; in-wave W3 reduction.

__global__ __launch_bounds__(TPB) void k_p2fb(const uint4* __restrict__ gb,
                                              const int2* __restrict__ rp2,
                                              const int* __restrict__ ssrc,
                                              const float* __restrict__ dinv,
                                              const int* __restrict__ perm,
                                              const float* __restrict__ b2,
                                              const float* __restrict__ W3,
                                              float* __restrict__ q4, int N) {
    int tid = blockIdx.x * TPB + threadIdx.x;
    int slot = tid >> 3, q = tid & 7;
    if (slot >= N) return;
    int node = perm[slot];                      // broadcast within group
    int2 r = rp2[node];
    int beg = r.x, end = r.y;
    float a[8];
    {
        uint4 u = gb[((size_t)node << 3) + q];  // self-loop
        a[0] = blo(u.x); a[1] = bhi(u.x);
        a[2] = blo(u.y); a[3] = bhi(u.y);
        a[4] = blo(u.z); a[5] = bhi(u.z);
        a[6] = blo(u.w); a[7] = bhi(u.w);
    }
    int j = beg;
    for (; j + 3 < end; j += 4) {
        int s0 = ssrc[j], s1 = ssrc[j+1], s2 = ssrc[j+2], s3 = ssrc[j+3];
        uint4 u0 = gb[((size_t)s0 << 3) + q];
        uint4 u1 = gb[((size_t)s1 << 3) + q];
        uint4 u2 = gb[((size_t)s2 << 3) + q];
        uint4 u3 = gb[((size_t)s3 << 3) + q];
        a[0] += (blo(u0.x) + blo(u1.x)) + (blo(u2.x) + blo(u3.x));
        a[1] += (bhi(u0.x) + bhi(u1.x)) + (bhi(u2.x) + bhi(u3.x));
        a[2] += (blo(u0.y) + blo(u1.y)) + (blo(u2.y) + blo(u3.y));
        a[3] += (bhi(u0.y) + bhi(u1.y)) + (bhi(u2.y) + bhi(u3.y));
        a[4] += (blo(u0.z) + blo(u1.z)) + (blo(u2.z) + blo(u3.z));
        a[5] += (bhi(u0.z) + bhi(u1.z)) + (bhi(u2.z) + bhi(u3.z));
        a[6] += (blo(u0.w) + blo(u1.w)) + (blo(u2.w) + blo(u3.w));
        a[7] += (bhi(u0.w) + bhi(u1.w)) + (bhi(u2.w) + bhi(u3.w));
    }
    for (; j < end; ++j) {
        uint4 u = gb[((size_t)ssrc[j] << 3) + q];
        a[0] += blo(u.x); a[1] += bhi(u.x);
        a[2] += blo(u.y); a[3] += bhi(u.y);
        a[4] += blo(u.z); a[5] += bhi(u.z);
        a[6] += blo(u.w); a[7] += bhi(u.w);
    }
    float dv = dinv[node];
    int f0 = q << 3;
    const float* bb = b2 + f0;
    const float* Wr = W3 + f0 * 3;
    float p0 = 0.f, p1 = 0.f, p2 = 0.f;
#pragma unroll
    for (int i = 0; i < 8; ++i) {
        float h = fmaxf(fmaf(a[i], dv, bb[i]), 0.f);
        p0 = fmaf(h, Wr[3*i+0], p0);
        p1 = fmaf(h, Wr[3*i+1], p1);
        p2 = fmaf(h, Wr[3*i+2], p2);
    }
#pragma unroll
    for (int off = 1; off < 8; off <<= 1) {
        p0 += __shfl_xor(p0, off, 64);
        p1 += __shfl_xor(p1, off, 64);
        p2 += __shfl_xor(p2, off, 64);
    }
    if (q < 4) {
        float v = (q == 0) ? p0 * dv : (q == 1) ? p1 * dv : (q == 2) ? p2 * dv : 0.f;
        q4[((size_t)node << 2) + q] = v;
    }
}

// ---------------- layer-3 pull with output epilogue (unpermuted) -----------

__global__ __launch_bounds__(TPB) void k_pull3o(const float* __restrict__ g34,
                                                const int2* __restrict__ rp2,
                                                const int* __restrict__ ssrc,
                                                const float* __restrict__ dinv,
                                                const float* __restrict__ b3,
                                                float* __restrict__ out, int N) {
    int tid = blockIdx.x * TPB + threadIdx.x;
    int node = tid >> 2, c = tid & 3;
    if (node >= N) return;
    int2 r = rp2[node];
    int beg = r.x, end = r.y;
    float acc = g34[tid];                       // self-loop
    int j = beg;
    for (; j + 3 < end; j += 4) {
        int s0 = ssrc[j], s1 = ssrc[j+1], s2 = ssrc[j+2], s3 = ssrc[j+3];
        acc += (g34[(s0 << 2) + c] + g34[(s1 << 2) + c])
             + (g34[(s2 << 2) + c] + g34[(s3 << 2) + c]);
    }
    for (; j < end; ++j) acc += g34[(ssrc[j] << 2) + c];
    if (c < 3) out[(size_t)node * 3 + c] = dinv[node] * acc + b3[c];
}

extern "C" void kernel_launch(void* const* d_in, const int* in_sizes, int n_in,
                              void* d_out, int out_size, void* d_ws, size_t ws_size,
                              hipStream_t stream) {
    const float* x  = (const float*)d_in[0];
    const int*   ei = (const int*)  d_in[1];
    const float* W1 = (const float*)d_in[2];
    const float* b1 = (const float*)d_in[3];
    const float* W2 = (const float*)d_in[4];
    const float* b2 = (const float*)d_in[5];
    const float* W3 = (const float*)d_in[6];
    const float* b3 = (const float*)d_in[7];
    float* out = (float*)d_out;

    const int N = in_sizes[0] / 3;       // 100000
    const int E = in_sizes[1] / 2;       // 1600000
    const int* srcI = ei;
    const int* dstI = ei + E;

    // workspace layout (4-byte units), 16B-aligned segments
    float*    ws   = (float*)d_ws;
    unsigned* gcur = (unsigned*)ws;                         // @0        [512]
    unsigned* gdh  = (unsigned*)(ws + 512);                 // @512      [64]
    unsigned* dcur = (unsigned*)(ws + 576);                 // @576      [64]
    int*      perm = (int*)     (ws + 640);                 // [N]
    int2*     rp2  = (int2*)    (ws + 640 + N);             // [N] (2N u32)
    float*    dinv = ws + 640 + 3 * (size_t)N;              // [N]
    int*      ssrc = (int*)     (dinv + N);                 // [NB*BS]
    float*    xs4  = (float*)(ssrc + (size_t)NB * BS);      // [4N]
    float*    q4   = xs4 + (size_t)N * 4;                   // [4N]
    float*    qx4  = q4  + (size_t)N * 4;                   // [4N]
    unsigned* gb   = (unsigned*)(qx4 + (size_t)N * 4);      // [32N] bf16 g
    unsigned* bkt  = gb + (size_t)N * 32;                   // [NB*BS]

    int gPlace = (E + CH - 1) / CH;                         // 391
    int gS3    = (N * 4 + TPB - 1) / TPB;                   // 1563
    int gP2    = (int)(((size_t)N * 8 + TPB - 1) / TPB);    // 3125
    int gN     = (N + TPB - 1) / TPB;                       // 391
    int gL1    = (N + 127) / 128;                           // 782

    // preprocessing: fixed-stride bucket sort -> rp2 + dinv + xs4 + deg hist
    hipMemsetAsync(gcur, 0, 576 * sizeof(unsigned), stream);
    k_placeA<<<gPlace, TPB, 0, stream>>>(srcI, dstI, gcur, bkt, E);
    k_fineS <<<NB,     512, 0, stream>>>(bkt, gcur, x, rp2, ssrc, dinv,
                                         (float4*)xs4, gdh, N);
    k_dscan <<<1,       64, 0, stream>>>(gdh, dcur);
    k_dperm <<<gN,     TPB, 0, stream>>>(rp2, dcur, perm, N);

    // layer 1: gather (natural order), then pure-VALU dense (scalar W2, f32)
    k_gq <<<gS3, TPB, 0, stream>>>(xs4, rp2, ssrc, dinv, qx4, N);
    k_l1d<<<gL1, TPB, 0, stream>>>((const float4*)qx4, W1, b1, W2,
                                   (uint4*)gb, N);

    // layer-2 pull (bf16, degree-desc perm) + bias/relu + layer-3 linear
    k_p2fb<<<gP2, TPB, 0, stream>>>((const uint4*)gb, rp2, ssrc, dinv, perm,
                                    b2, W3, q4, N);

    // layer-3 pull (+bias fused)
    k_pull3o<<<gS3, TPB, 0, stream>>>(q4, rp2, ssrc, dinv, b3, out, N);
}